// Round 8
// baseline (1275.017 us; speedup 1.0000x reference)
//
#include <hip/hip_runtime.h>
#include <hip/hip_bf16.h>
#include <hip/hip_fp16.h>

#define NF 128
#define RBF 20

using short8 = __attribute__((ext_vector_type(8))) short;
using f32x4  = __attribute__((ext_vector_type(4))) float;

__device__ __forceinline__ float sspf(float v) {
    return fmaxf(v, 0.f) + log1pf(__expf(-fabsf(v))) - 0.69314718055994531f;
}
__device__ __forceinline__ unsigned short f2bf(float f) {
    union { float f; unsigned u; } v; v.f = f;
    unsigned r = v.u + 0x7fffu + ((v.u >> 16) & 1u);
    return (unsigned short)(r >> 16);
}
__device__ __forceinline__ float bf2f(unsigned short s) {
    union { unsigned u; float f; } v; v.u = ((unsigned)s) << 16;
    return v.f;
}

// ---------------------------------------------------------------------------
// Edge kernel (persistent, 512 threads = 8 waves, 16 cols/wave):
//   phase1 (MFMA): h = ssp(f @ W1 + b1)        (K padded 20->32)
//   phase2 (MFMA, TRANSPOSED): wijT = W2^T @ h^T -> lane owns 4 consecutive
//           cols of ONE edge -> packed gathers (uint2) + packed half2 atomics
//   phase3: gather bf16 xf/yf + fp16x2 atomic scatter into conv (half)
// ---------------------------------------------------------------------------
__global__ __launch_bounds__(512, 4)
void edge_mfma_kernel(const float* __restrict__ f_ij,
                      const float* __restrict__ rcut,
                      const int* __restrict__ idx_i,
                      const int* __restrict__ idx_j,
                      const float* __restrict__ Wf1,
                      const float* __restrict__ bf1,
                      const float* __restrict__ Wf2,
                      const float* __restrict__ bf2v,
                      const unsigned short* __restrict__ xf,
                      const unsigned short* __restrict__ yf,
                      __half* __restrict__ conv_x,
                      __half* __restrict__ conv_y,
                      int E, int nTiles)
{
    const int tid = threadIdx.x;
    const int l = tid & 63, w = tid >> 6;       // 8 waves
    const int lr = l & 15, lk = l >> 4;
    const int wcol0 = w * 16;                   // wave's 16-col slice
    const int wcol = wcol0 + lr;                // col used in phase-1 epilogue
    const int c0 = wcol0 + lk * 4;              // phase-3: 4 consecutive cols

    __shared__ unsigned short f16[64 * 32];     // 4 KB
    __shared__ unsigned short Ash[64 * NF];     // 16 KB (swizzled h)
    __shared__ int io_s[64], jo_s[64];
    __shared__ float rc_s[64];

    // persistent weight fragments (per wave: 16 cols)
    short8 b1fr;
    #pragma unroll
    for (int j = 0; j < 8; ++j) {
        const int k = lk * 8 + j;
        b1fr[j] = (k < RBF) ? (short)f2bf(Wf1[k * NF + wcol]) : (short)0;
    }
    short8 b2fr[4];
    #pragma unroll
    for (int kb = 0; kb < 4; ++kb)
        #pragma unroll
        for (int j = 0; j < 8; ++j)
            b2fr[kb][j] = (short)f2bf(Wf2[(size_t)(kb * 32 + lk * 8 + j) * NF + wcol]);
    const float b1c = bf1[wcol];
    float b2q[4];
    #pragma unroll
    for (int q = 0; q < 4; ++q) b2q[q] = bf2v[c0 + q];

    for (int tile = blockIdx.x; tile < nTiles; tile += gridDim.x) {
        const int e0 = tile * 64;
        __syncthreads();                        // prev-tile LDS readers done
        #pragma unroll
        for (int s = 0; s < 4; ++s) {           // 2048 elems / 512 thr
            const int t = s * 512 + tid;
            const int row = t >> 5, k = t & 31;
            float v = 0.f;
            if (k < RBF && e0 + row < E) v = f_ij[(size_t)(e0 + row) * RBF + k];
            f16[t] = f2bf(v);
        }
        if (tid < 64) {
            const int e = min(e0 + tid, E - 1);
            io_s[tid] = idx_i[e] * NF;
            jo_s[tid] = idx_j[e] * NF;
            rc_s[tid] = rcut[e];
        }
        __syncthreads();

        // phase 1: h = ssp(f @ W1 + b1)  (normal orientation)
        f32x4 acc1[4] = {};
        #pragma unroll
        for (int rb = 0; rb < 4; ++rb) {
            const short8 a = *reinterpret_cast<const short8*>(
                &f16[(rb * 16 + lr) * 32 + lk * 8]);
            acc1[rb] = __builtin_amdgcn_mfma_f32_16x16x32_bf16(a, b1fr, acc1[rb], 0, 0, 0);
        }
        #pragma unroll
        for (int rb = 0; rb < 4; ++rb)
            #pragma unroll
            for (int q = 0; q < 4; ++q) {
                const int e = rb * 16 + lk * 4 + q;
                const float hv = sspf(acc1[rb][q] + b1c);
                Ash[e * NF + (wcol ^ ((e & 7) << 3))] = f2bf(hv);
            }
        __syncthreads();

        // phase 2 (transposed): D = W2^T x h^T ; lane -> edge rb*16+lr,
        // cols c0..c0+3 (acc[rb][q] = col c0+q)
        f32x4 acc[4] = {};
        #pragma unroll
        for (int rb = 0; rb < 4; ++rb) {
            short8 a[4];
            #pragma unroll
            for (int kb = 0; kb < 4; ++kb) {
                const int e  = rb * 16 + lr;
                const int k0 = kb * 32 + lk * 8;
                a[kb] = *reinterpret_cast<const short8*>(
                    &Ash[e * NF + (k0 ^ ((e & 7) << 3))]);
            }
            #pragma unroll
            for (int kb = 0; kb < 4; ++kb)
                acc[rb] = __builtin_amdgcn_mfma_f32_16x16x32_bf16(
                    b2fr[kb], a[kb], acc[rb], 0, 0, 0);   // swapped operands
        }

        // phase 3: packed gather + packed half2 atomic scatter
        #pragma unroll
        for (int rb = 0; rb < 4; ++rb) {
            const int e = rb * 16 + lr;
            if (e0 + e < E) {
                const int io = io_s[e], jo = jo_s[e];
                const float rc = rc_s[e];
                const uint2 gya = *reinterpret_cast<const uint2*>(&yf[(size_t)jo + c0]);
                const uint2 gxb = *reinterpret_cast<const uint2*>(&xf[(size_t)io + c0]);
                float wv[4];
                #pragma unroll
                for (int q = 0; q < 4; ++q)
                    wv[q] = (acc[rb][q] + b2q[q]) * rc;

                const float ga0 = bf2f((unsigned short)(gya.x & 0xffff));
                const float ga1 = bf2f((unsigned short)(gya.x >> 16));
                const float ga2 = bf2f((unsigned short)(gya.y & 0xffff));
                const float ga3 = bf2f((unsigned short)(gya.y >> 16));
                const float gb0 = bf2f((unsigned short)(gxb.x & 0xffff));
                const float gb1 = bf2f((unsigned short)(gxb.x >> 16));
                const float gb2 = bf2f((unsigned short)(gxb.y & 0xffff));
                const float gb3 = bf2f((unsigned short)(gxb.y >> 16));

                __half2* px = reinterpret_cast<__half2*>(&conv_x[(size_t)io + c0]);
                __half2* py = reinterpret_cast<__half2*>(&conv_y[(size_t)jo + c0]);
                unsafeAtomicAdd(px,     __floats2half2_rn(ga0 * wv[0], ga1 * wv[1]));
                unsafeAtomicAdd(px + 1, __floats2half2_rn(ga2 * wv[2], ga3 * wv[3]));
                unsafeAtomicAdd(py,     __floats2half2_rn(gb0 * wv[0], gb1 * wv[1]));
                unsafeAtomicAdd(py + 1, __floats2half2_rn(gb2 * wv[2], gb3 * wv[3]));
            }
        }
    }
}

// ---------------------------------------------------------------------------
// Projection (persistent): out_bf16 = in @ W (bias-free) + zero conv (half)
// ---------------------------------------------------------------------------
__global__ __launch_bounds__(256, 2)
void proj_mfma_kernel(const float* in0, const float* in1,
                      const float* __restrict__ W0, const float* __restrict__ W1p,
                      unsigned short* o0, unsigned short* o1,
                      __half* convz0, __half* convz1, int N, int nTiles)
{
    const float* in = blockIdx.y ? in1 : in0;
    const float* W  = blockIdx.y ? W1p : W0;
    unsigned short* out = blockIdx.y ? o1 : o0;
    __half* convz       = blockIdx.y ? convz1 : convz0;

    const int tid = threadIdx.x;
    const int l = tid & 63, w = tid >> 6;
    const int lr = l & 15, lk = l >> 4;
    const int wcol0 = w * 32;

    __shared__ unsigned short Ahi[64 * NF];

    short8 bfr[4][2];
    #pragma unroll
    for (int kb = 0; kb < 4; ++kb)
        #pragma unroll
        for (int cb = 0; cb < 2; ++cb) {
            const int col = wcol0 + cb * 16 + lr;
            #pragma unroll
            for (int j = 0; j < 8; ++j)
                bfr[kb][cb][j] = (short)f2bf(W[(size_t)(kb * 32 + lk * 8 + j) * NF + col]);
        }

    for (int tile = blockIdx.x; tile < nTiles; tile += gridDim.x) {
        const int n0 = tile * 64;
        __syncthreads();
        #pragma unroll
        for (int s = 0; s < 32; ++s) {
            const int t = s * 256 + tid;
            const int row = t >> 7, cc = t & (NF - 1);
            const float v = (n0 + row < N) ? in[(size_t)(n0 + row) * NF + cc] : 0.f;
            Ahi[row * NF + (cc ^ ((row & 7) << 3))] = f2bf(v);
        }
        // zero conv rows of this tile (half): 64 rows x 128 halves = 1024 uint4
        {
            const uint4 z = {0u, 0u, 0u, 0u};
            const size_t lim = (size_t)N * 16;       // uint4 count
            #pragma unroll
            for (int s = 0; s < 4; ++s) {
                const size_t off = (size_t)n0 * 16 + (size_t)(s * 256 + tid);
                if (off < lim) reinterpret_cast<uint4*>(convz)[off] = z;
            }
        }
        __syncthreads();

        f32x4 acc[4][2] = {};
        #pragma unroll
        for (int rb = 0; rb < 4; ++rb) {
            short8 a[4];
            #pragma unroll
            for (int kb = 0; kb < 4; ++kb) {
                const int e  = rb * 16 + lr;
                const int k0 = kb * 32 + lk * 8;
                a[kb] = *reinterpret_cast<const short8*>(&Ahi[e * NF + (k0 ^ ((e & 7) << 3))]);
            }
            #pragma unroll
            for (int cb = 0; cb < 2; ++cb)
                #pragma unroll
                for (int kb = 0; kb < 4; ++kb)
                    acc[rb][cb] = __builtin_amdgcn_mfma_f32_16x16x32_bf16(
                        a[kb], bfr[kb][cb], acc[rb][cb], 0, 0, 0);
        }

        #pragma unroll
        for (int rb = 0; rb < 4; ++rb)
            #pragma unroll
            for (int cb = 0; cb < 2; ++cb) {
                const int col = wcol0 + cb * 16 + lr;
                #pragma unroll
                for (int q = 0; q < 4; ++q) {
                    const int n = n0 + rb * 16 + lk * 4 + q;
                    if (n < N) out[(size_t)n * NF + col] = f2bf(acc[rb][cb][q]);
                }
            }
    }
}

// ---------------------------------------------------------------------------
// Fused output MLP (persistent): out = ssp(conv @ W1 + b1) @ W2 + b2
// conv is fp16; staged as split-bf16 (hi/lo) A.
// ---------------------------------------------------------------------------
__global__ __launch_bounds__(256, 2)
void out_fused_kernel(const __half* conv0, const __half* conv1,
                      const float* __restrict__ W10, const float* __restrict__ W11,
                      const float* __restrict__ b10, const float* __restrict__ b11,
                      const float* __restrict__ W20, const float* __restrict__ W21,
                      const float* __restrict__ b20, const float* __restrict__ b21,
                      float* o0, float* o1, int N, int nTiles)
{
    const __half* in = blockIdx.y ? conv1 : conv0;
    const float* W1 = blockIdx.y ? W11 : W10;
    const float* b1 = blockIdx.y ? b11 : b10;
    const float* W2 = blockIdx.y ? W21 : W20;
    const float* b2 = blockIdx.y ? b21 : b20;
    float* out      = blockIdx.y ? o1  : o0;

    const int tid = threadIdx.x;
    const int l = tid & 63, w = tid >> 6;
    const int lr = l & 15, lk = l >> 4;
    const int wcol0 = w * 32;

    __shared__ unsigned short Ahi[64 * NF];
    __shared__ unsigned short Alo[64 * NF];

    short8 w1fr[4][2], w2fr[4][2];
    #pragma unroll
    for (int kb = 0; kb < 4; ++kb)
        #pragma unroll
        for (int cb = 0; cb < 2; ++cb) {
            const int col = wcol0 + cb * 16 + lr;
            #pragma unroll
            for (int j = 0; j < 8; ++j) {
                const size_t kk = (size_t)(kb * 32 + lk * 8 + j) * NF + col;
                w1fr[kb][cb][j] = (short)f2bf(W1[kk]);
                w2fr[kb][cb][j] = (short)f2bf(W2[kk]);
            }
        }
    const float b1c0 = b1[wcol0 + lr], b1c1 = b1[wcol0 + 16 + lr];
    const float b2c0 = b2[wcol0 + lr], b2c1 = b2[wcol0 + 16 + lr];

    for (int tile = blockIdx.x; tile < nTiles; tile += gridDim.x) {
        const int n0 = tile * 64;
        __syncthreads();
        // stage conv (half) -> split-bf16: 64x128 halves = 4096 uints
        #pragma unroll
        for (int s = 0; s < 16; ++s) {
            const int t = s * 256 + tid;
            const int row = t >> 6, cp = t & 63;        // col-pair index
            uint u = 0;
            if (n0 + row < N)
                u = reinterpret_cast<const uint*>(in)[(size_t)(n0 + row) * 64 + cp];
            const __half2 h2 = *reinterpret_cast<const __half2*>(&u);
            const float2 f2 = __half22float2(h2);
            const int cc = cp * 2;
            const int idx = row * NF + (cc ^ ((row & 7) << 3));  // pair stays adjacent
            const unsigned short hi0 = f2bf(f2.x);
            const unsigned short hi1 = f2bf(f2.y);
            Ahi[idx] = hi0; Ahi[idx + 1] = hi1;
            Alo[idx]     = f2bf(f2.x - bf2f(hi0));
            Alo[idx + 1] = f2bf(f2.y - bf2f(hi1));
        }
        __syncthreads();

        f32x4 acc1[4][2] = {};
        #pragma unroll
        for (int rb = 0; rb < 4; ++rb) {
            short8 ah[4], al[4];
            #pragma unroll
            for (int kb = 0; kb < 4; ++kb) {
                const int e  = rb * 16 + lr;
                const int k0 = kb * 32 + lk * 8;
                const int idx = e * NF + (k0 ^ ((e & 7) << 3));
                ah[kb] = *reinterpret_cast<const short8*>(&Ahi[idx]);
                al[kb] = *reinterpret_cast<const short8*>(&Alo[idx]);
            }
            #pragma unroll
            for (int cb = 0; cb < 2; ++cb)
                #pragma unroll
                for (int kb = 0; kb < 4; ++kb) {
                    acc1[rb][cb] = __builtin_amdgcn_mfma_f32_16x16x32_bf16(
                        ah[kb], w1fr[kb][cb], acc1[rb][cb], 0, 0, 0);
                    acc1[rb][cb] = __builtin_amdgcn_mfma_f32_16x16x32_bf16(
                        al[kb], w1fr[kb][cb], acc1[rb][cb], 0, 0, 0);
                }
        }
        __syncthreads();

        #pragma unroll
        for (int rb = 0; rb < 4; ++rb)
            #pragma unroll
            for (int cb = 0; cb < 2; ++cb) {
                const int col = wcol0 + cb * 16 + lr;
                #pragma unroll
                for (int q = 0; q < 4; ++q) {
                    const int e = rb * 16 + lk * 4 + q;
                    const float hv = sspf(acc1[rb][cb][q] + (cb ? b1c1 : b1c0));
                    const unsigned short hi = f2bf(hv);
                    const int idx = e * NF + (col ^ ((e & 7) << 3));
                    Ahi[idx] = hi;
                    Alo[idx] = f2bf(hv - bf2f(hi));
                }
            }
        __syncthreads();

        f32x4 acc2[4][2] = {};
        #pragma unroll
        for (int rb = 0; rb < 4; ++rb) {
            short8 ah[4], al[4];
            #pragma unroll
            for (int kb = 0; kb < 4; ++kb) {
                const int e  = rb * 16 + lr;
                const int k0 = kb * 32 + lk * 8;
                const int idx = e * NF + (k0 ^ ((e & 7) << 3));
                ah[kb] = *reinterpret_cast<const short8*>(&Ahi[idx]);
                al[kb] = *reinterpret_cast<const short8*>(&Alo[idx]);
            }
            #pragma unroll
            for (int cb = 0; cb < 2; ++cb)
                #pragma unroll
                for (int kb = 0; kb < 4; ++kb) {
                    acc2[rb][cb] = __builtin_amdgcn_mfma_f32_16x16x32_bf16(
                        ah[kb], w2fr[kb][cb], acc2[rb][cb], 0, 0, 0);
                    acc2[rb][cb] = __builtin_amdgcn_mfma_f32_16x16x32_bf16(
                        al[kb], w2fr[kb][cb], acc2[rb][cb], 0, 0, 0);
                }
        }

        #pragma unroll
        for (int rb = 0; rb < 4; ++rb)
            #pragma unroll
            for (int cb = 0; cb < 2; ++cb) {
                const int col = wcol0 + cb * 16 + lr;
                #pragma unroll
                for (int q = 0; q < 4; ++q) {
                    const int n = n0 + rb * 16 + lk * 4 + q;
                    if (n < N)
                        out[(size_t)n * NF + col] = acc2[rb][cb][q] + (cb ? b2c1 : b2c0);
                }
            }
    }
}

extern "C" void kernel_launch(void* const* d_in, const int* in_sizes, int n_in,
                              void* d_out, int out_size, void* d_ws, size_t ws_size,
                              hipStream_t stream)
{
    const float* x    = (const float*)d_in[0];
    const float* y    = (const float*)d_in[1];
    const float* f_ij = (const float*)d_in[2];
    const float* rcut = (const float*)d_in[3];
    const int* idx_i  = (const int*)d_in[4];
    const int* idx_j  = (const int*)d_in[5];
    const float* W_in2f   = (const float*)d_in[6];
    const float* W_in2f_y = (const float*)d_in[7];
    const float* Wf1 = (const float*)d_in[8];
    const float* bf1 = (const float*)d_in[9];
    const float* Wf2 = (const float*)d_in[10];
    const float* bf2 = (const float*)d_in[11];
    const float* Wx1 = (const float*)d_in[12];
    const float* bx1 = (const float*)d_in[13];
    const float* Wx2 = (const float*)d_in[14];
    const float* bx2 = (const float*)d_in[15];
    const float* Wy1 = (const float*)d_in[16];
    const float* by1 = (const float*)d_in[17];
    const float* Wy2 = (const float*)d_in[18];
    const float* by2 = (const float*)d_in[19];

    const int N = in_sizes[0] / NF;
    const int E = in_sizes[4];

    unsigned short* xf = (unsigned short*)d_out;
    unsigned short* yf = xf + (size_t)N * NF;
    float* ox = (float*)d_out;
    float* oy = ox + (size_t)N * NF;

    __half* conv_x = (__half*)d_ws;               // [N*NF] fp16
    __half* conv_y = conv_x + (size_t)N * NF;

    const int nodeTiles = (N + 63) / 64;
    const int edgeTiles = (E + 63) / 64;

    proj_mfma_kernel<<<dim3(1024, 2), 256, 0, stream>>>(
        x, y, W_in2f, W_in2f_y, xf, yf, conv_x, conv_y, N, nodeTiles);

    edge_mfma_kernel<<<dim3(1024), 512, 0, stream>>>(
        f_ij, rcut, idx_i, idx_j, Wf1, bf1, Wf2, bf2, xf, yf,
        conv_x, conv_y, E, edgeTiles);

    out_fused_kernel<<<dim3(1024, 2), 256, 0, stream>>>(
        conv_x, conv_y, Wx1, Wy1, bx1, by1, Wx2, Wy2, bx2, by2,
        ox, oy, N, nodeTiles);
}